// Round 18
// baseline (19.244 us; speedup 1.0000x reference)
//
#include <hip/hip_runtime.h>

// NeighborsConvolution: out[z,a,i] = sum_{b,x,j} [|r_b-r_a|<0.5] * (r_b-r_a)_x * W[x,i,j] * feat[z,b,j]
// B=8, N=1024, CIN=COUT=64.
//
// R18 = R16 (best, 18.08us) + bit-exact instruction diet on scan/consume:
//  - geo stored SoA-packed in LDS: gxy as float2[1024], gz as float[1024].
//    Scan: 2 LDS reads/step (b64+b32) vs 3; consume: 2 uniform reads vs 3.
//  - packed scan math: pk_sub/pk_mul for (x,y); d2 = (sq.x+sq.y) + dz*dz
//    under fp contract(off) -- every op same IEEE f32, same left-assoc order
//    as before -> ballot masks bit-identical.
//  - consume keeps scalar fmaf (bit-safety); its subs go packed (pk_sub exact).
//  - Shell identical to R16: 512 blocks x 1024 thr (32 waves/CU cap), 60KB LDS,
//    one-pass W stage, xj-split epilogue, 4 barriers.

#define BATCHSZ 8
#define NPTS 1024
#define CIN 64
#define COUT 64
#define NXJ (3 * CIN)      // 192
#define NG (NXJ / 4)       // 48 float4 groups
#define WPB 16             // waves (points) per block
#define BS (WPB * 64)      // 1024 threads
#define GPW (NG / 8)       // 6 W-groups per wave (xj-split within 8-wave half)
#define NSTEP (NPTS / 64)  // 16 ballot steps

typedef float f32x2 __attribute__((ext_vector_type(2)));

// smem layout (floats), 15360 floats = 60KB:
//  [0,2048)      gxy (float2[1024])  \ both dead after process ->
//  [2048,3072)   gz  (float[1024])   /  overlaid by tmp[16][192] (3072 floats)
//  [3072,15360)  wstage 48KB -> after pickups: red0 @3072, red1 @7168
#define SM_WS 3072
#define SM_TOTAL 15360

__global__ __launch_bounds__(BS, 8) void neigh_conv_kernel(
    const float* __restrict__ feat,  // [B,N,CIN]
    const float* __restrict__ geom,  // [B,N,3]
    const float* __restrict__ W,     // [3,COUT,CIN]
    float* __restrict__ out)         // [B,N,COUT]
{
    const int lane = threadIdx.x & 63;
    const int wv   = threadIdx.x >> 6;    // 0..15
    const int h    = wv >> 3;             // half 0/1
    const int hw   = wv & 7;              // wave within half
    const int p    = blockIdx.x * WPB + wv;
    const int a    = p & (NPTS - 1);
    const int z    = p >> 10;              // uniform across block (16 | 1024)

    __shared__ __align__(16) float smem[SM_TOTAL];

    // ---- prologue: stage geo (SoA xy/z) + ALL of W (swizzled); 1 barrier ----
    {
        const float* gsrc = geom + (size_t)z * NPTS * 3;
        const int b = threadIdx.x;                    // BS == NPTS == 1024
        const float x0 = gsrc[b * 3 + 0];
        const float y0 = gsrc[b * 3 + 1];
        const float z0 = gsrc[b * 3 + 2];
        f32x2 xy; xy.x = x0; xy.y = y0;
        *(f32x2*)&smem[2 * b] = xy;
        smem[2048 + b] = z0;

        const float4* w4 = (const float4*)W;          // 3072 float4
        float4* ws = (float4*)(smem + SM_WS);
        #pragma unroll
        for (int kk = 0; kk < 3; ++kk) {              // 3 independent loads
            const int k = threadIdx.x + kk * BS;
            // rotate swizzle: row i=k>>4, slot j4=k&15 -> (j4+i)&15
            const int idx = (k & ~15) | ((k + (k >> 4)) & 15);
            ws[idx] = w4[k];
        }
    }
    __syncthreads();   // B1: geo + wstage visible

    // ---- W fragment pickup (rotated b128 reads; once per wave) ----
    const int g0 = hw * GPW;
    float4 wr[GPW];
    {
        const float4* ws = (const float4*)(smem + SM_WS);
        #pragma unroll
        for (int q = 0; q < GPW; ++q) {
            const int g = g0 + q;
            const int x = g >> 4, c = g & 15;
            wr[q] = ws[x * 1024 + (lane << 4) + ((c + lane) & 15)];
        }
    }

    const f32x2* gxy = (const f32x2*)smem;
    const float* gzz = smem + 2048;
    const f32x2 gaf2 = gxy[a];           // uniform b64 broadcast
    const float gaz  = gzz[a];
    const float* fz = feat + (size_t)z * NPTS * CIN;

    // ---- scan: 16 ballot steps; masks live wave-uniform (SGPR pairs) ----
    unsigned long long masks[NSTEP];
    #pragma unroll
    for (int ss = 0; ss < NSTEP; ++ss) {
        const int b = ss * 64 + lane;
        float d2;
        {
            // Bit-exact vs numpy near boundary: no contraction; pk ops are
            // per-component IEEE f32; add order (dx2+dy2)+dz2 == left-assoc.
            #pragma clang fp contract(off)
            const f32x2 dxy = gxy[b] - gaf2;   // pk_sub, stride-8B: conflict-free
            const float dz  = gzz[b] - gaz;
            const f32x2 sq  = dxy * dxy;       // pk_mul
            d2 = (sq.x + sq.y) + dz * dz;
        }
        masks[ss] = __ballot(d2 < 0.25f);
    }

    // ---- process: depth-2 pipelined mask-walk (2 feat loads in flight) ----
    float acc0 = 0.f, acc1 = 0.f, acc2 = 0.f;
    int   b1 = -1, b2 = -1;
    float f1 = 0.f, f2 = 0.f;

    auto consume = [&](int bc, float fc) {
        const f32x2 dxy = gxy[bc] - gaf2;    // uniform broadcast + pk_sub (exact)
        const float dz  = gzz[bc] - gaz;
        acc0 = fmaf(dxy.x, fc, acc0);        // bit-identical to R16's fmaf chain
        acc1 = fmaf(dxy.y, fc, acc1);
        acc2 = fmaf(dz,    fc, acc2);
    };

    #pragma unroll
    for (int ss = 0; ss < NSTEP; ++ss) {
        unsigned long long mm = masks[ss];
        while (mm) {                     // wave-uniform scalar walk
            const int src = __ffsll(mm) - 1;
            mm &= mm - 1ull;
            const int b = ss * 64 + src;
            const float f = fz[(size_t)b * CIN + lane];  // issue load NOW
            if (b2 >= 0) consume(b2, f2);
            b2 = b1; f2 = f1;            // shift pipeline (reg moves only)
            b1 = b;  f1 = f;
        }
    }
    if (b2 >= 0) consume(b2, f2);        // drain (ascending order preserved)
    if (b1 >= 0) consume(b1, f1);

    __syncthreads();   // B2a: ALL waves done reading geo -> region reusable

    float* tmp = smem + wv * NXJ;        // tmp[16][192] overlays geo
    tmp[0 * CIN + lane] = acc0;
    tmp[1 * CIN + lane] = acc1;
    tmp[2 * CIN + lane] = acc2;
    __syncthreads();   // B2b: tmps visible; wstage pickups long done -> red ok

    // ---- epilogue: per half, wave hw owns groups [6hw,6hw+6), 8 points ----
    float* red = smem + SM_WS + h * (8 * 8 * COUT);   // 16KB per half
    #pragma unroll
    for (int pp = 0; pp < 8; ++pp) {
        const float4* t4 = (const float4*)(smem + (h * 8 + pp) * NXJ);
        f32x2 facc = {0.f, 0.f};
        #pragma unroll
        for (int q = 0; q < GPW; ++q) {
            const float4 t = t4[g0 + q];          // uniform -> LDS broadcast
            f32x2 ta; ta.x = t.x; ta.y = t.y;
            f32x2 tb; tb.x = t.z; tb.y = t.w;
            f32x2 wa; wa.x = wr[q].x; wa.y = wr[q].y;
            f32x2 wb; wb.x = wr[q].z; wb.y = wr[q].w;
            facc = ta * wa + facc;                // v_pk_fma_f32
            facc = tb * wb + facc;
        }
        red[(hw * 8 + pp) * COUT + lane] = facc.x + facc.y;
    }
    __syncthreads();   // B3

    // ---- reduce within half + store ----
    float o = 0.f;
    #pragma unroll
    for (int w = 0; w < 8; ++w)
        o += red[(w * 8 + hw) * COUT + lane];     // 2 lanes/bank: free

    out[(size_t)p * COUT + lane] = o;
}

extern "C" void kernel_launch(void* const* d_in, const int* in_sizes, int n_in,
                              void* d_out, int out_size, void* d_ws, size_t ws_size,
                              hipStream_t stream) {
    const float* feat = (const float*)d_in[0];  // [8,1024,64]
    const float* geom = (const float*)d_in[1];  // [8,1024,3]
    const float* W    = (const float*)d_in[2];  // [3,64,64]
    float* out        = (float*)d_out;          // [8,1024,64]

    const int nblocks = BATCHSZ * NPTS / WPB;   // 512 blocks x 1024 threads
    neigh_conv_kernel<<<nblocks, BS, 0, stream>>>(feat, geom, W, out);
}

// Round 19
// 18.091 us; speedup vs baseline: 1.0637x; 1.0637x over previous
//
#include <hip/hip_runtime.h>

// NeighborsConvolution: out[z,a,i] = sum_{b,x,j} [|r_b-r_a|<0.5] * (r_b-r_a)_x * W[x,i,j] * feat[z,b,j]
// B=8, N=1024, CIN=COUT=64.
//
// FINAL = R16 (best measured: 18.08us). Restored verbatim after R17/R18
// regressions. Structure:
//  - 512 blocks x 1024 threads (16 waves) @60KB LDS -> 2 blocks/CU = 32
//    waves/CU (occupancy cap). 16 points per block.
//  - Prologue: geo (12KB float4) + ALL of W (48KB, rotate-swizzled, one pass,
//    3 float4/thread) staged with ONE barrier.
//  - Scan: 16 ballot steps, masks in wave-uniform SGPRs, stride-3 LDS reads
//    (conflict-free), fp contract(off) left-assoc d2 -> mask bit-exact vs numpy.
//  - Process: depth-2 software-pipelined mask-walk, 2 coalesced feat loads in
//    flight, consume via uniform LDS broadcast diffs (bit-identical subs).
//  - Epilogue: xj-split across 8-wave halves (wave hw owns W-groups
//    [6hw,6hw+6), computes partials for 8 points), red in dead wstage LDS,
//    cross-wave reduce. v_pk_fma_f32 packed math.
// Floor ledger: F~8us (launch+ramp+prologue), W~10us (issue/interleave floor;
// VALUBusy~43% work-weighted, HBM 6%, 0 bank conflicts, occupancy at cap;
// R12/R13/R17 latency restructures null, R18 instruction diet regressed).

#define BATCHSZ 8
#define NPTS 1024
#define CIN 64
#define COUT 64
#define NXJ (3 * CIN)      // 192
#define NG (NXJ / 4)       // 48 float4 groups
#define WPB 16             // waves (points) per block
#define BS (WPB * 64)      // 1024 threads
#define GPW (NG / 8)       // 6 W-groups per wave (xj-split within 8-wave half)
#define NSTEP (NPTS / 64)  // 16 ballot steps

typedef float f32x2 __attribute__((ext_vector_type(2)));

// smem layout (floats), 15360 floats = 60KB:
//  [0,3072)      geo (12KB)  -> after process-drain barrier: tmp[16][192]
//  [3072,15360)  wstage 48KB -> after pickups: red0 @3072, red1 @7168 (16KB ea)
#define SM_WS 3072
#define SM_TOTAL 15360

__global__ __launch_bounds__(BS, 8) void neigh_conv_kernel(
    const float* __restrict__ feat,  // [B,N,CIN]
    const float* __restrict__ geom,  // [B,N,3]
    const float* __restrict__ W,     // [3,COUT,CIN]
    float* __restrict__ out)         // [B,N,COUT]
{
    const int lane = threadIdx.x & 63;
    const int wv   = threadIdx.x >> 6;    // 0..15
    const int h    = wv >> 3;             // half 0/1
    const int hw   = wv & 7;              // wave within half
    const int p    = blockIdx.x * WPB + wv;
    const int a    = p & (NPTS - 1);
    const int z    = p >> 10;              // uniform across block (16 | 1024)

    __shared__ __align__(16) float smem[SM_TOTAL];

    // ---- prologue: stage geo (12KB) + ALL of W (48KB, swizzled); 1 barrier ----
    {
        const float4* gsrc = (const float4*)(geom + (size_t)z * NPTS * 3);
        float4* gdst = (float4*)smem;
        if (threadIdx.x < NPTS * 3 / 4)               // 768 of 1024 threads
            gdst[threadIdx.x] = gsrc[threadIdx.x];

        const float4* w4 = (const float4*)W;          // 3072 float4
        float4* ws = (float4*)(smem + SM_WS);
        #pragma unroll
        for (int kk = 0; kk < 3; ++kk) {              // 3 independent loads
            const int k = threadIdx.x + kk * BS;
            // rotate swizzle: row i=k>>4, slot j4=k&15 -> (j4+i)&15
            const int idx = (k & ~15) | ((k + (k >> 4)) & 15);
            ws[idx] = w4[k];
        }
    }
    __syncthreads();   // B1: geo + wstage visible

    // ---- W fragment pickup (rotated b128 reads; once per wave) ----
    const int g0 = hw * GPW;
    float4 wr[GPW];
    {
        const float4* ws = (const float4*)(smem + SM_WS);
        #pragma unroll
        for (int q = 0; q < GPW; ++q) {
            const int g = g0 + q;
            const int x = g >> 4, c = g & 15;
            wr[q] = ws[x * 1024 + (lane << 4) + ((c + lane) & 15)];
        }
    }

    const float* geo = smem;
    const float gax = geo[a * 3 + 0];
    const float gay = geo[a * 3 + 1];
    const float gaz = geo[a * 3 + 2];
    const float* fz = feat + (size_t)z * NPTS * CIN;

    // ---- scan: 16 ballot steps; masks live wave-uniform (SGPR pairs) ----
    unsigned long long masks[NSTEP];
    #pragma unroll
    for (int ss = 0; ss < NSTEP; ++ss) {
        const int b = ss * 64 + lane;
        float d2;
        {
            // Bit-exact vs numpy near boundary: no contraction, left-assoc.
            #pragma clang fp contract(off)
            const float dx = geo[b * 3 + 0] - gax;   // stride-3: conflict-free
            const float dy = geo[b * 3 + 1] - gay;
            const float dz = geo[b * 3 + 2] - gaz;
            d2 = dx * dx + dy * dy + dz * dz;
        }
        masks[ss] = __ballot(d2 < 0.25f);
    }

    // ---- process: depth-2 pipelined mask-walk (2 feat loads in flight) ----
    float acc0 = 0.f, acc1 = 0.f, acc2 = 0.f;
    int   b1 = -1, b2 = -1;
    float f1 = 0.f, f2 = 0.f;

    auto consume = [&](int bc, float fc) {
        const float gbx = geo[bc * 3 + 0];   // uniform addr -> LDS broadcast
        const float gby = geo[bc * 3 + 1];
        const float gbz = geo[bc * 3 + 2];
        const float dx = gbx - gax;          // bit-identical to scan's diff
        const float dy = gby - gay;
        const float dz = gbz - gaz;
        acc0 = fmaf(dx, fc, acc0);
        acc1 = fmaf(dy, fc, acc1);
        acc2 = fmaf(dz, fc, acc2);
    };

    #pragma unroll
    for (int ss = 0; ss < NSTEP; ++ss) {
        unsigned long long mm = masks[ss];
        while (mm) {                     // wave-uniform scalar walk
            const int src = __ffsll(mm) - 1;
            mm &= mm - 1ull;
            const int b = ss * 64 + src;
            const float f = fz[(size_t)b * CIN + lane];  // issue load NOW
            if (b2 >= 0) consume(b2, f2);
            b2 = b1; f2 = f1;            // shift pipeline (reg moves only)
            b1 = b;  f1 = f;
        }
    }
    if (b2 >= 0) consume(b2, f2);        // drain (ascending order preserved)
    if (b1 >= 0) consume(b1, f1);

    __syncthreads();   // B2a: ALL waves done reading geo -> region reusable

    float* tmp = smem + wv * NXJ;        // tmp[16][192] overlays geo
    tmp[0 * CIN + lane] = acc0;
    tmp[1 * CIN + lane] = acc1;
    tmp[2 * CIN + lane] = acc2;
    __syncthreads();   // B2b: tmps visible; wstage pickups long done -> red ok

    // ---- epilogue: per half, wave hw owns groups [6hw,6hw+6), 8 points ----
    float* red = smem + SM_WS + h * (8 * 8 * COUT);   // 16KB per half
    #pragma unroll
    for (int pp = 0; pp < 8; ++pp) {
        const float4* t4 = (const float4*)(smem + (h * 8 + pp) * NXJ);
        f32x2 facc = {0.f, 0.f};
        #pragma unroll
        for (int q = 0; q < GPW; ++q) {
            const float4 t = t4[g0 + q];          // uniform -> LDS broadcast
            f32x2 ta; ta.x = t.x; ta.y = t.y;
            f32x2 tb; tb.x = t.z; tb.y = t.w;
            f32x2 wa; wa.x = wr[q].x; wa.y = wr[q].y;
            f32x2 wb; wb.x = wr[q].z; wb.y = wr[q].w;
            facc = ta * wa + facc;                // v_pk_fma_f32
            facc = tb * wb + facc;
        }
        red[(hw * 8 + pp) * COUT + lane] = facc.x + facc.y;
    }
    __syncthreads();   // B3

    // ---- reduce within half + store ----
    float o = 0.f;
    #pragma unroll
    for (int w = 0; w < 8; ++w)
        o += red[(w * 8 + hw) * COUT + lane];     // 2 lanes/bank: free

    out[(size_t)p * COUT + lane] = o;
}

extern "C" void kernel_launch(void* const* d_in, const int* in_sizes, int n_in,
                              void* d_out, int out_size, void* d_ws, size_t ws_size,
                              hipStream_t stream) {
    const float* feat = (const float*)d_in[0];  // [8,1024,64]
    const float* geom = (const float*)d_in[1];  // [8,1024,3]
    const float* W    = (const float*)d_in[2];  // [3,64,64]
    float* out        = (float*)d_out;          // [8,1024,64]

    const int nblocks = BATCHSZ * NPTS / WPB;   // 512 blocks x 1024 threads
    neigh_conv_kernel<<<nblocks, BS, 0, stream>>>(feat, geom, W, out);
}